// Round 5
// baseline (541.934 us; speedup 1.0000x reference)
//
#include <hip/hip_runtime.h>
#include <hip/hip_bf16.h>

// EdgeApplyModule: out[e] = relu(concat(node[src[e]], edge[e], node[dst[e]]) @ W + b)
// N_EDGES=1e6, D_NODE=D_EDGE=D_OUT=64, D_IN=192. f32 in/out; bf16 MFMA compute.
//
// R4: R2 profile showed latency-bound (all pipes <10%, ~400B/wave in flight by
// Little's law). This round: software pipeline — idx prefetch depth 2, row-data
// prefetch depth 1 (12xfloat4/lane reg buffer), launch_bounds(256,4) to hold
// 4 waves/SIMD, opaque B offset to stop LICM hoisting B-frags into 96 VGPRs.

typedef __attribute__((ext_vector_type(8))) short short8;
typedef __attribute__((ext_vector_type(4))) float f32x4;

#define D 64
#define DIN 192
#define BM 64      // edges per chunk
#define GRID 2048  // grid-stride over 15625 chunks

__device__ __forceinline__ short bf_bits(float f) {
  __hip_bfloat16 h = __float2bfloat16(f);  // RNE
  union { __hip_bfloat16 b; short s; } u; u.b = h;
  return u.s;
}

// Pre-arrange W (f32 [192][64] row-major) into bf16 MFMA B-fragment layout:
// wsB[((t*4 + c)*64 + l)*8 + s] = bf16(W[32t + (l>>4)*8 + s][16c + (l&15)])
__global__ void prep_W_kernel(const float* __restrict__ W,
                              unsigned short* __restrict__ wsB) {
  int i = blockIdx.x * blockDim.x + threadIdx.x;
  if (i >= DIN * D) return;
  int k = i >> 6;          // 0..191
  int n = i & 63;          // 0..63
  int t = k >> 5;
  int g = (k >> 3) & 3;
  int s = k & 7;
  int c = n >> 4;
  int l = g * 16 + (n & 15);
  wsB[(((t << 2) + c) * 64 + l) * 8 + s] = (unsigned short)bf_bits(W[i]);
}

__global__ __launch_bounds__(256, 4) void edge_mlp_kernel(
    const float* __restrict__ node_feat,   // [100000][64]
    const float* __restrict__ edge_feat,   // [1e6][64]
    const int*   __restrict__ src_idx,     // [1e6]
    const int*   __restrict__ dst_idx,     // [1e6]
    const unsigned short* __restrict__ wsB,// [6][4][64][8] bf16 bits
    const float* __restrict__ bias,        // [64]
    float* __restrict__ out,               // [1e6][64]
    int nE) {
  const int tid = threadIdx.x;
  const int w = tid >> 6;       // wave 0..3
  const int l = tid & 63;       // lane
  const int g = l >> 4;         // k-group 0..3
  const int r = l & 15;         // A-row / B-col within tile
  const int rowIC = w * 16 + r; // lane's edge-row within a 64-edge chunk
  const int gofs = g * 8;       // lane's float offset within each 32-float half

  const short8* B = reinterpret_cast<const short8*>(wsB);
  const int nChunks = (nE + BM - 1) / BM;  // 15625
  const int G = gridDim.x;

  const float bn0 = bias[r], bn1 = bias[16 + r], bn2 = bias[32 + r],
              bn3 = bias[48 + r];

  float4 X[12];        // prefetched row data for the chunk about to be computed
  int si1, di1, ec1;   // prefetched indices for the NEXT chunk's row issue

  int c = blockIdx.x;

  // ---- prologue: idx(c) -> rows(c) in flight -> idx(c+G) prefetched ----
  {
    long e0 = (long)c * BM + rowIC;
    int eL = e0 < nE ? (int)e0 : nE - 1;
    si1 = src_idx[eL];
    di1 = dst_idx[eL];
    ec1 = eL;
  }
  {
    const float* pS = node_feat + (size_t)si1 * D + gofs;
    const float* pE = edge_feat + (size_t)ec1 * D + gofs;
    const float* pD = node_feat + (size_t)di1 * D + gofs;
    X[0]  = *reinterpret_cast<const float4*>(pS);
    X[1]  = *reinterpret_cast<const float4*>(pS + 4);
    X[2]  = *reinterpret_cast<const float4*>(pS + 32);
    X[3]  = *reinterpret_cast<const float4*>(pS + 36);
    X[4]  = *reinterpret_cast<const float4*>(pE);
    X[5]  = *reinterpret_cast<const float4*>(pE + 4);
    X[6]  = *reinterpret_cast<const float4*>(pE + 32);
    X[7]  = *reinterpret_cast<const float4*>(pE + 36);
    X[8]  = *reinterpret_cast<const float4*>(pD);
    X[9]  = *reinterpret_cast<const float4*>(pD + 4);
    X[10] = *reinterpret_cast<const float4*>(pD + 32);
    X[11] = *reinterpret_cast<const float4*>(pD + 36);
  }
  {
    long e1 = (long)(c + G) * BM + rowIC;
    int eL = e1 < nE ? (int)e1 : nE - 1;
    si1 = src_idx[eL];
    di1 = dst_idx[eL];
    ec1 = eL;
  }

  for (; c < nChunks; c += G) {
    // ---- 1. cvt X (rows of chunk c) -> bf16 A-frags (waits on row loads) ----
    short8 A[6];
    #pragma unroll
    for (int t = 0; t < 6; ++t) {
      float4 x = X[2 * t], y = X[2 * t + 1];
      A[t][0] = bf_bits(x.x); A[t][1] = bf_bits(x.y);
      A[t][2] = bf_bits(x.z); A[t][3] = bf_bits(x.w);
      A[t][4] = bf_bits(y.x); A[t][5] = bf_bits(y.y);
      A[t][6] = bf_bits(y.z); A[t][7] = bf_bits(y.w);
    }

    // ---- 2. issue rows(c+G) + prefetch idx(c+2G); block-uniform guard ----
    if (c + G < nChunks) {
      const float* pS = node_feat + (size_t)si1 * D + gofs;
      const float* pE = edge_feat + (size_t)ec1 * D + gofs;
      const float* pD = node_feat + (size_t)di1 * D + gofs;
      X[0]  = *reinterpret_cast<const float4*>(pS);
      X[1]  = *reinterpret_cast<const float4*>(pS + 4);
      X[2]  = *reinterpret_cast<const float4*>(pS + 32);
      X[3]  = *reinterpret_cast<const float4*>(pS + 36);
      X[4]  = *reinterpret_cast<const float4*>(pE);
      X[5]  = *reinterpret_cast<const float4*>(pE + 4);
      X[6]  = *reinterpret_cast<const float4*>(pE + 32);
      X[7]  = *reinterpret_cast<const float4*>(pE + 36);
      X[8]  = *reinterpret_cast<const float4*>(pD);
      X[9]  = *reinterpret_cast<const float4*>(pD + 4);
      X[10] = *reinterpret_cast<const float4*>(pD + 32);
      X[11] = *reinterpret_cast<const float4*>(pD + 36);

      long e2 = (long)(c + 2 * G) * BM + rowIC;
      int eL = e2 < nE ? (int)e2 : nE - 1;
      si1 = src_idx[eL];
      di1 = dst_idx[eL];
      ec1 = eL;
    }

    // ---- 3. MFMA (B-frags reloaded from L1-hot wsB each iteration) ----
    // opaque offset: stop LICM from hoisting 24 B-frag loads into 96 VGPRs
    int bofs = 0;
    asm volatile("" : "+v"(bofs));
    const short8* B2 = B + bofs;

    f32x4 acc[4];
    #pragma unroll
    for (int cc = 0; cc < 4; ++cc) acc[cc] = (f32x4){0.f, 0.f, 0.f, 0.f};

    #pragma unroll
    for (int t = 0; t < 6; ++t) {
      short8 b0 = B2[(t * 4 + 0) * 64 + l];
      short8 b1 = B2[(t * 4 + 1) * 64 + l];
      short8 b2 = B2[(t * 4 + 2) * 64 + l];
      short8 b3 = B2[(t * 4 + 3) * 64 + l];
      acc[0] = __builtin_amdgcn_mfma_f32_16x16x32_bf16(A[t], b0, acc[0], 0, 0, 0);
      acc[1] = __builtin_amdgcn_mfma_f32_16x16x32_bf16(A[t], b1, acc[1], 0, 0, 0);
      acc[2] = __builtin_amdgcn_mfma_f32_16x16x32_bf16(A[t], b2, acc[2], 0, 0, 0);
      acc[3] = __builtin_amdgcn_mfma_f32_16x16x32_bf16(A[t], b3, acc[3], 0, 0, 0);
    }

    // ---- 4. epilogue: C/D layout col = lane&15, row = (lane>>4)*4 + reg ----
    const long baseW = (long)c * BM + w * 16;
    const float bns[4] = {bn0, bn1, bn2, bn3};
    #pragma unroll
    for (int cc = 0; cc < 4; ++cc) {
      const int n = cc * 16 + r;
      #pragma unroll
      for (int j = 0; j < 4; ++j) {
        long eo = baseW + g * 4 + j;
        if (eo < nE) {
          float v = acc[cc][j] + bns[cc];
          out[eo * D + n] = v > 0.f ? v : 0.f;
        }
      }
    }
  }
}

extern "C" void kernel_launch(void* const* d_in, const int* in_sizes, int n_in,
                              void* d_out, int out_size, void* d_ws, size_t ws_size,
                              hipStream_t stream) {
  const float* node_feat = (const float*)d_in[0];
  const float* edge_feat = (const float*)d_in[1];
  const int*   src_idx   = (const int*)d_in[2];
  const int*   dst_idx   = (const int*)d_in[3];
  const float* W         = (const float*)d_in[4];
  const float* bias      = (const float*)d_in[5];
  float* out = (float*)d_out;
  unsigned short* wsB = (unsigned short*)d_ws;  // needs 6*4*64*8*2 = 24576 B

  const int nE = in_sizes[2];  // 1,000,000

  hipLaunchKernelGGL(prep_W_kernel, dim3((DIN * D + 255) / 256), dim3(256), 0,
                     stream, W, wsB);

  const int nChunks = (nE + BM - 1) / BM;  // 15625
  const int grid = nChunks < GRID ? nChunks : GRID;
  hipLaunchKernelGGL(edge_mlp_kernel, dim3(grid), dim3(256), 0, stream,
                     node_feat, edge_feat, src_idx, dst_idx, wsB, bias, out, nE);
}

// Round 9
// 482.816 us; speedup vs baseline: 1.1224x; 1.1224x over previous
//
#include <hip/hip_runtime.h>
#include <hip/hip_bf16.h>

// EdgeApplyModule: out[e] = relu(concat(node[src[e]], edge[e], node[dst[e]]) @ W + b)
// N_EDGES=1e6, D_NODE=D_EDGE=D_OUT=64, D_IN=192. f32 in/out; bf16 MFMA compute.
//
// R6: R5 post-mortem — regalloc serialized register prefetch (VGPR 64), waves
// stuck at ~4KB in flight/CU. Fix: global_load_lds gathers into wave-private
// LDS X buffer (zero VGPR cost for in-flight data, can't be serialized), B
// staged in LDS (lgkmcnt-tracked, so no in-loop vmcnt wait traps the older
// GLLs — vmcnt retires in order). Explicit vmcnt(0)/lgkmcnt(0)+sched_barrier
// fences (rule #18). grid=512 (2 blocks/CU by 72KB LDS) => all co-resident.

typedef __attribute__((ext_vector_type(8))) short short8;
typedef __attribute__((ext_vector_type(4))) float f32x4;

#define D 64
#define DIN 192
#define BM 64     // edges per chunk (16 per wave)
#define GRID 512  // 2 blocks/CU * 256 CU, all resident; grid-stride 15625 chunks

__device__ __forceinline__ short bf_bits(float f) {
  __hip_bfloat16 h = __float2bfloat16(f);  // RNE
  union { __hip_bfloat16 b; short s; } u; u.b = h;
  return u.s;
}

// async global->LDS, 16B per lane; LDS dest = wave-uniform base + lane*16
__device__ __forceinline__ void gll16(const void* g, void* l) {
  __builtin_amdgcn_global_load_lds(
      (const __attribute__((address_space(1))) void*)g,
      (__attribute__((address_space(3))) void*)l, 16, 0, 0);
}

// Pre-arrange W (f32 [192][64] row-major) into bf16 MFMA B-fragment layout:
// wsB[((t*4 + c)*64 + l)*8 + s] = bf16(W[32t + (l>>4)*8 + s][16c + (l&15)])
__global__ void prep_W_kernel(const float* __restrict__ W,
                              unsigned short* __restrict__ wsB) {
  int i = blockIdx.x * blockDim.x + threadIdx.x;
  if (i >= DIN * D) return;
  int k = i >> 6;          // 0..191
  int n = i & 63;          // 0..63
  int t = k >> 5;
  int g = (k >> 3) & 3;
  int s = k & 7;
  int c = n >> 4;
  int l = g * 16 + (n & 15);
  wsB[(((t << 2) + c) * 64 + l) * 8 + s] = (unsigned short)bf_bits(W[i]);
}

__global__ __launch_bounds__(256, 2) void edge_mlp_kernel(
    const float* __restrict__ node_feat,   // [100000][64]
    const float* __restrict__ edge_feat,   // [1e6][64]
    const int*   __restrict__ src_idx,     // [1e6]
    const int*   __restrict__ dst_idx,     // [1e6]
    const unsigned short* __restrict__ wsB,// [6][4][64][8] bf16 bits
    const float* __restrict__ bias,        // [64]
    float* __restrict__ out,               // [1e6][64]
    int nE) {
  __shared__ short8 Bs[24][64];           // 24576 B, B fragments
  __shared__ float  Xs[4][12][64][4];     // 49152 B, wave-private gather buffers

  const int tid = threadIdx.x;
  const int w = tid >> 6;       // wave 0..3
  const int l = tid & 63;       // lane
  const int g = l >> 4;         // k-group 0..3
  const int r = l & 15;         // A-row / B-col within tile
  const int rowIC = w * 16 + r; // lane's edge-row within a 64-edge chunk
  const int gofs = g * 8;       // lane's float offset within each 32-float half

  // ---- stage B into LDS once (block-cooperative), single barrier ----
  {
    const short8* Bsrc = reinterpret_cast<const short8*>(wsB);
    short8* Bdst = &Bs[0][0];
    for (int j = tid; j < 24 * 64; j += 256) Bdst[j] = Bsrc[j];
  }
  __syncthreads();  // no barriers after this; waves drift independently

  const int nChunks = (nE + BM - 1) / BM;  // 15625
  const int G = gridDim.x;

  const float bn0 = bias[r], bn1 = bias[16 + r], bn2 = bias[32 + r],
              bn3 = bias[48 + r];

  int c = blockIdx.x;

  // ---- prologue: idx(c) -> issue GLL(c) -> prefetch idx(c+G) ----
  int siN, diN, ecN;
  {
    long e0 = (long)c * BM + rowIC;
    int eL = e0 < nE ? (int)e0 : nE - 1;
    int si = src_idx[eL];
    int di = dst_idx[eL];
    const float* pS = node_feat + (size_t)si * D + gofs;
    const float* pE = edge_feat + (size_t)eL * D + gofs;
    const float* pD = node_feat + (size_t)di * D + gofs;
    gll16(pS,      &Xs[w][0][0][0]);
    gll16(pS + 4,  &Xs[w][1][0][0]);
    gll16(pS + 32, &Xs[w][2][0][0]);
    gll16(pS + 36, &Xs[w][3][0][0]);
    gll16(pE,      &Xs[w][4][0][0]);
    gll16(pE + 4,  &Xs[w][5][0][0]);
    gll16(pE + 32, &Xs[w][6][0][0]);
    gll16(pE + 36, &Xs[w][7][0][0]);
    gll16(pD,      &Xs[w][8][0][0]);
    gll16(pD + 4,  &Xs[w][9][0][0]);
    gll16(pD + 32, &Xs[w][10][0][0]);
    gll16(pD + 36, &Xs[w][11][0][0]);
  }
  {
    long e1 = (long)(c + G) * BM + rowIC;
    int eL = e1 < nE ? (int)e1 : nE - 1;
    siN = src_idx[eL];
    diN = dst_idx[eL];
    ecN = eL;
  }

  for (; c < nChunks; c += G) {
    // ---- GLL(c) landed in LDS; idx(c+G) regs ready ----
    asm volatile("s_waitcnt vmcnt(0)" ::: "memory");
    __builtin_amdgcn_sched_barrier(0);

    // ---- cvt X(c) -> bf16 A-frags (ds_read_b128, conflict-free) ----
    short8 A[6];
    #pragma unroll
    for (int t = 0; t < 6; ++t) {
      float4 x = *reinterpret_cast<const float4*>(&Xs[w][2 * t][l][0]);
      float4 y = *reinterpret_cast<const float4*>(&Xs[w][2 * t + 1][l][0]);
      A[t][0] = bf_bits(x.x); A[t][1] = bf_bits(x.y);
      A[t][2] = bf_bits(x.z); A[t][3] = bf_bits(x.w);
      A[t][4] = bf_bits(y.x); A[t][5] = bf_bits(y.y);
      A[t][6] = bf_bits(y.z); A[t][7] = bf_bits(y.w);
    }

    // ---- X buffer free (all ds_reads retired) -> reissue GLL(c+G) ----
    asm volatile("s_waitcnt lgkmcnt(0)" ::: "memory");
    __builtin_amdgcn_sched_barrier(0);

    if (c + G < nChunks) {  // block-uniform
      const float* pS = node_feat + (size_t)siN * D + gofs;
      const float* pE = edge_feat + (size_t)ecN * D + gofs;
      const float* pD = node_feat + (size_t)diN * D + gofs;
      gll16(pS,      &Xs[w][0][0][0]);
      gll16(pS + 4,  &Xs[w][1][0][0]);
      gll16(pS + 32, &Xs[w][2][0][0]);
      gll16(pS + 36, &Xs[w][3][0][0]);
      gll16(pE,      &Xs[w][4][0][0]);
      gll16(pE + 4,  &Xs[w][5][0][0]);
      gll16(pE + 32, &Xs[w][6][0][0]);
      gll16(pE + 36, &Xs[w][7][0][0]);
      gll16(pD,      &Xs[w][8][0][0]);
      gll16(pD + 4,  &Xs[w][9][0][0]);
      gll16(pD + 32, &Xs[w][10][0][0]);
      gll16(pD + 36, &Xs[w][11][0][0]);

      long e2 = (long)(c + 2 * G) * BM + rowIC;
      int eL = e2 < nE ? (int)e2 : nE - 1;
      siN = src_idx[eL];   // prefetch idx(c+2G); drained by next top vmcnt(0)
      diN = dst_idx[eL];
      ecN = eL;
    }

    // ---- MFMA; B from LDS (lgkmcnt-tracked -> GLLs stay in flight) ----
    f32x4 acc[4];
    #pragma unroll
    for (int cc = 0; cc < 4; ++cc) acc[cc] = (f32x4){0.f, 0.f, 0.f, 0.f};

    #pragma unroll
    for (int t = 0; t < 6; ++t) {
      short8 b0 = Bs[t * 4 + 0][l];
      short8 b1 = Bs[t * 4 + 1][l];
      short8 b2 = Bs[t * 4 + 2][l];
      short8 b3 = Bs[t * 4 + 3][l];
      acc[0] = __builtin_amdgcn_mfma_f32_16x16x32_bf16(A[t], b0, acc[0], 0, 0, 0);
      acc[1] = __builtin_amdgcn_mfma_f32_16x16x32_bf16(A[t], b1, acc[1], 0, 0, 0);
      acc[2] = __builtin_amdgcn_mfma_f32_16x16x32_bf16(A[t], b2, acc[2], 0, 0, 0);
      acc[3] = __builtin_amdgcn_mfma_f32_16x16x32_bf16(A[t], b3, acc[3], 0, 0, 0);
    }

    // ---- epilogue: C/D layout col = lane&15, row = (lane>>4)*4 + reg ----
    const long baseW = (long)c * BM + w * 16;
    const float bns[4] = {bn0, bn1, bn2, bn3};
    #pragma unroll
    for (int cc = 0; cc < 4; ++cc) {
      const int n = cc * 16 + r;
      #pragma unroll
      for (int j = 0; j < 4; ++j) {
        long eo = baseW + g * 4 + j;
        if (eo < nE) {
          float v = acc[cc][j] + bns[cc];
          out[eo * D + n] = v > 0.f ? v : 0.f;
        }
      }
    }
  }
}

extern "C" void kernel_launch(void* const* d_in, const int* in_sizes, int n_in,
                              void* d_out, int out_size, void* d_ws, size_t ws_size,
                              hipStream_t stream) {
  const float* node_feat = (const float*)d_in[0];
  const float* edge_feat = (const float*)d_in[1];
  const int*   src_idx   = (const int*)d_in[2];
  const int*   dst_idx   = (const int*)d_in[3];
  const float* W         = (const float*)d_in[4];
  const float* bias      = (const float*)d_in[5];
  float* out = (float*)d_out;
  unsigned short* wsB = (unsigned short*)d_ws;  // needs 6*4*64*8*2 = 24576 B

  const int nE = in_sizes[2];  // 1,000,000

  hipLaunchKernelGGL(prep_W_kernel, dim3((DIN * D + 255) / 256), dim3(256), 0,
                     stream, W, wsB);

  const int nChunks = (nE + BM - 1) / BM;  // 15625
  const int grid = nChunks < GRID ? nChunks : GRID;
  hipLaunchKernelGGL(edge_mlp_kernel, dim3(grid), dim3(256), 0, stream,
                     node_feat, edge_feat, src_idx, dst_idx, wsB, bias, out, nE);
}